// Round 1
// baseline (449.018 us; speedup 1.0000x reference)
//
#include <hip/hip_runtime.h>
#include <hip/hip_bf16.h>

#define NH 64
#define JT 4

__device__ __forceinline__ float fast_tanh(float x) {
  float ax = fabsf(x);
  float e  = __expf(-2.0f * ax);
  float y  = (1.0f - e) * __builtin_amdgcn_rcpf(1.0f + e);
  return copysignf(y, x);
}

// Fold layer-1 monomials into W2: Wk[h][j][k] = W2[h][j] * mono(h,k)
// mono = [1, a, b, a^2, ab, b^2, a^3, a^2 b, a b^2, b^3], a = W1[0][h], b = W1[1][h]
__global__ void prep_kernel(const float* __restrict__ W1,
                            const float* __restrict__ W2,
                            float* __restrict__ Wk) {
  int idx = blockIdx.x * blockDim.x + threadIdx.x;
  if (idx >= NH * NH * 10) return;
  int k = idx % 10;
  int j = (idx / 10) % NH;
  int h = idx / (NH * 10);
  float a = W1[h];
  float b = W1[NH + h];
  float m = 1.0f;
  switch (k) {
    case 0: m = 1.0f;      break;
    case 1: m = a;         break;
    case 2: m = b;         break;
    case 3: m = a * a;     break;
    case 4: m = a * b;     break;
    case 5: m = b * b;     break;
    case 6: m = a * a * a; break;
    case 7: m = a * a * b; break;
    case 8: m = a * b * b; break;
    case 9: m = b * b * b; break;
  }
  Wk[idx] = W2[h * NH + j] * m;
}

__global__ __launch_bounds__(128, 2) void pinn_kernel(
    const float* __restrict__ phi, const float* __restrict__ theta,
    const float* __restrict__ radius, const float* __restrict__ hth,
    const float* __restrict__ hph, const float* __restrict__ br,
    const float* __restrict__ W1, const float* __restrict__ b1,
    const float* __restrict__ b2, const float* __restrict__ W3,
    const float* __restrict__ Wk, float* __restrict__ out, int n) {
  // per-thread y[h] stored in LDS (own column only; no cross-thread use, no sync)
  __shared__ float ylds[NH * 128];
  const int tid = threadIdx.x;
  const int i = blockIdx.x * 128 + tid;
  if (i >= n) return;

  const float p = phi[i];
  const float t = theta[i];

  // ---- layer 1: y[h] = tanh(a*p + b*t + b1) ----
  for (int h = 0; h < NH; ++h) {
    float z = fmaf(p, W1[h], fmaf(t, W1[NH + h], b1[h]));
    ylds[h * 128 + tid] = fast_tanh(z);
  }

  // T-jet accumulators (value unused downstream)
  float T_p = 0.f, T_t = 0.f, T_pp = 0.f, T_pt = 0.f, T_tt = 0.f;
  float T_ppp = 0.f, T_ppt = 0.f, T_ptt = 0.f, T_ttt = 0.f;

  for (int j0 = 0; j0 < NH; j0 += JT) {
    float z0[JT], zp[JT], zt[JT], zpp[JT], zpt[JT], ztt[JT];
    float zppp[JT], zppt[JT], zptt[JT], zttt[JT];
#pragma unroll
    for (int jj = 0; jj < JT; ++jj) {
      z0[jj] = b2[j0 + jj];
      zp[jj] = zt[jj] = zpp[jj] = zpt[jj] = ztt[jj] = 0.f;
      zppp[jj] = zppt[jj] = zptt[jj] = zttt[jj] = 0.f;
    }
    for (int h = 0; h < NH; ++h) {
      float yv = ylds[h * 128 + tid];
      float f1 = fmaf(-yv, yv, 1.0f);          // tanh'
      float f2 = -2.0f * (yv * f1);            // tanh''
      float f3 = f1 * fmaf(6.0f * yv, yv, -2.0f); // tanh'''
      const float* w = Wk + (h * NH + j0) * 10;
#pragma unroll
      for (int jj = 0; jj < JT; ++jj) {
        z0[jj]   = fmaf(w[jj * 10 + 0], yv, z0[jj]);
        zp[jj]   = fmaf(w[jj * 10 + 1], f1, zp[jj]);
        zt[jj]   = fmaf(w[jj * 10 + 2], f1, zt[jj]);
        zpp[jj]  = fmaf(w[jj * 10 + 3], f2, zpp[jj]);
        zpt[jj]  = fmaf(w[jj * 10 + 4], f2, zpt[jj]);
        ztt[jj]  = fmaf(w[jj * 10 + 5], f2, ztt[jj]);
        zppp[jj] = fmaf(w[jj * 10 + 6], f3, zppp[jj]);
        zppt[jj] = fmaf(w[jj * 10 + 7], f3, zppt[jj]);
        zptt[jj] = fmaf(w[jj * 10 + 8], f3, zptt[jj]);
        zttt[jj] = fmaf(w[jj * 10 + 9], f3, zttt[jj]);
      }
    }
    // ---- layer 2 tanh jet (Faa di Bruno, order 3) + W3 contraction ----
#pragma unroll
    for (int jj = 0; jj < JT; ++jj) {
      float y2 = fast_tanh(z0[jj]);
      float g1 = fmaf(-y2, y2, 1.0f);
      float g2 = -2.0f * (y2 * g1);
      float g3 = g1 * fmaf(6.0f * y2, y2, -2.0f);
      float gp = zp[jj], gt = zt[jj];
      float gpp = zpp[jj], gpt = zpt[jj], gtt = ztt[jj];
      float gp2 = gp * gp, gt2 = gt * gt;
      float w3 = W3[j0 + jj];
      T_p  = fmaf(w3, g1 * gp, T_p);
      T_t  = fmaf(w3, g1 * gt, T_t);
      T_pp = fmaf(w3, fmaf(g2, gp2, g1 * gpp), T_pp);
      T_pt = fmaf(w3, fmaf(g2, gp * gt, g1 * gpt), T_pt);
      T_tt = fmaf(w3, fmaf(g2, gt2, g1 * gtt), T_tt);
      T_ppp = fmaf(w3, fmaf(g3, gp2 * gp, fmaf(3.0f * g2, gp * gpp, g1 * zppp[jj])), T_ppp);
      T_ppt = fmaf(w3, fmaf(g3, gp2 * gt, fmaf(g2, fmaf(2.0f, gp * gpt, gt * gpp), g1 * zppt[jj])), T_ppt);
      T_ptt = fmaf(w3, fmaf(g3, gp * gt2, fmaf(g2, fmaf(2.0f, gt * gpt, gp * gtt), g1 * zptt[jj])), T_ptt);
      T_ttt = fmaf(w3, fmaf(g3, gt2 * gt, fmaf(3.0f * g2, gt * gtt, g1 * zttt[jj])), T_ttt);
    }
  }

  // ---- epilogue (analytic equivalents of the reference grad chain) ----
  float s = sinf(t), c = cosf(t);
  float inv_s = 1.0f / s;
  float inv_s2 = inv_s * inv_s;

  float A = T_p * inv_s + T_t;          // u_theta
  float D = T_p * inv_s - T_t;          // u_phi
  float q1 = T_pt * inv_s - T_p * c * inv_s2;             // dt(T_p/s)
  float A_t = q1 + T_tt;
  float D_t = q1 - T_tt;
  float q2 = T_ptt * inv_s - 2.0f * T_pt * c * inv_s2
           + T_p * (s * s + 2.0f * c * c) * inv_s2 * inv_s; // dtt(T_p/s)
  float A_tt = q2 + T_ttt;
  float D_tt = q2 - T_ttt;
  float A_pp = T_ppp * inv_s + T_ppt;
  float D_p  = T_pp * inv_s - T_pt;
  float D_pp = T_ppp * inv_s - T_ppt;

  float utt   = -(A_t * s + A * c);                              // u_theta_theta
  float uttt  = -(A_tt * s + 2.0f * A_t * c - A * s) * s + utt * c; // u_theta_theta_theta
  float utpp  = -A_pp;                                           // u_theta_phi_phi
  float upht  = D_t * s + D * c;                                 // u_phi_theta
  float uphtt = (D_tt * s + 2.0f * D_t * c - D * s) * s + upht * c; // u_phi_theta_theta
  float upp   = D_p;                                             // u_phi_phi
  float uppp  = D_pp;                                            // u_phi_phi_phi

  float r = radius[i];
  float inv_r = 1.0f / r;
  float inv_r2 = inv_r * inv_r;
  float div_uh = (utt + upp) * inv_r * inv_s;
  float lap_t = s * inv_r2 * uttt + utpp * inv_s2 * inv_r2;
  float lap_p = s * inv_r2 * uphtt + uppp * inv_s2 * inv_r2;
  float comp = s * (lap_t * lap_t + lap_p * lap_p);
  float sv = -(A * hth[i] + D * hph[i]) - br[i] * div_uh;
  float tg = div_uh - A * (s / c) * inv_r;

  out[i]         = A;
  out[n + i]     = D;
  out[2 * n + i] = div_uh;
  out[3 * n + i] = sv;
  out[4 * n + i] = tg;
  out[5 * n + i] = comp;
}

extern "C" void kernel_launch(void* const* d_in, const int* in_sizes, int n_in,
                              void* d_out, int out_size, void* d_ws, size_t ws_size,
                              hipStream_t stream) {
  const float* phi    = (const float*)d_in[0];
  const float* theta  = (const float*)d_in[1];
  const float* radius = (const float*)d_in[2];
  const float* hth    = (const float*)d_in[3];
  const float* hph    = (const float*)d_in[4];
  const float* br     = (const float*)d_in[5];
  const float* W1     = (const float*)d_in[6];
  const float* b1     = (const float*)d_in[7];
  const float* W2     = (const float*)d_in[8];
  const float* b2     = (const float*)d_in[9];
  const float* W3     = (const float*)d_in[10];
  const float* b3     = (const float*)d_in[11];
  (void)b3; (void)ws_size; (void)n_in; (void)out_size;

  float* Wk = (float*)d_ws;           // 64*64*10 floats = 160 KB
  float* out = (float*)d_out;
  int n = in_sizes[0];

  prep_kernel<<<(NH * NH * 10 + 255) / 256, 256, 0, stream>>>(W1, W2, Wk);
  pinn_kernel<<<(n + 127) / 128, 128, 0, stream>>>(
      phi, theta, radius, hth, hph, br, W1, b1, b2, W3, Wk, out, n);
}

// Round 2
// 225.615 us; speedup vs baseline: 1.9902x; 1.9902x over previous
//
#include <hip/hip_runtime.h>
#include <hip/hip_bf16.h>

#define NH 64

__device__ __forceinline__ float fast_tanh(float x) {
  float ax = fabsf(x);
  float e  = __expf(-2.0f * ax);
  float y  = (1.0f - e) * __builtin_amdgcn_rcpf(1.0f + e);
  return copysignf(y, x);
}

// Precompute monomials of layer-1 weights: mono = [1,a,b,a^2,ab,b^2,a^3,a^2b,ab^2,b^3]
// padded to 12 floats/row for 16-B-aligned scalar loads.
__global__ void prep_mono(const float* __restrict__ W1, float* __restrict__ Wm) {
  int h = threadIdx.x;
  if (h >= NH) return;
  float a = W1[h];
  float b = W1[NH + h];
  float* m = Wm + h * 12;
  m[0] = 1.0f; m[1] = a;         m[2] = b;
  m[3] = a * a; m[4] = a * b;    m[5] = b * b;
  m[6] = a * a * a; m[7] = a * a * b; m[8] = a * b * b; m[9] = b * b * b;
  m[10] = 0.0f; m[11] = 0.0f;
}

// Block = 256 threads = 4 waves, handles 64 points.
// wave w owns j-range [16w, 16w+16); lane l owns point blockIdx*64 + l.
__global__ __launch_bounds__(256) void pinn_kernel(
    const float* __restrict__ phi, const float* __restrict__ theta,
    const float* __restrict__ radius, const float* __restrict__ hth,
    const float* __restrict__ hph, const float* __restrict__ br,
    const float* __restrict__ W1, const float* __restrict__ b1,
    const float* __restrict__ W2, const float* __restrict__ b2,
    const float* __restrict__ W3, const float* __restrict__ Wm,
    float* __restrict__ out, int n) {
  __shared__ float ylds[NH * 64];      // y[h][point]   16 KB
  __shared__ float red[9 * 4 * 64];    // partial T-derivs [kind][wave][point]  9 KB

  const int tid  = threadIdx.x;
  const int lane = tid & 63;
  const int wave = __builtin_amdgcn_readfirstlane(tid >> 6);
  const int pi   = blockIdx.x * 64 + lane;

  float p = 0.0f, t = 0.0f;
  if (pi < n) { p = phi[pi]; t = theta[pi]; }

  // ---- phase 1: layer-1 activations, wave w computes h in [16w,16w+16) ----
  for (int k = 0; k < 16; ++k) {
    int h = wave * 16 + k;            // wave-uniform
    float z = fmaf(p, W1[h], fmaf(t, W1[NH + h], b1[h]));
    ylds[h * 64 + lane] = fast_tanh(z);
  }
  __syncthreads();

  // ---- phase 2: jet through layer 2 for this wave's 16 j's ----
  const int jbase = wave * 16;
  float T_p = 0.f, T_t = 0.f, T_pp = 0.f, T_pt = 0.f, T_tt = 0.f;
  float T_ppp = 0.f, T_ppt = 0.f, T_ptt = 0.f, T_ttt = 0.f;

  for (int jb = 0; jb < 4; ++jb) {
    const int j0 = jbase + jb * 4;    // wave-uniform
    float z0[4], zp[4], zt[4], zpp[4], zpt[4], ztt[4];
    float zppp[4], zppt[4], zptt[4], zttt[4];
#pragma unroll
    for (int jj = 0; jj < 4; ++jj) {
      z0[jj] = b2[j0 + jj];
      zp[jj] = zt[jj] = zpp[jj] = zpt[jj] = ztt[jj] = 0.f;
      zppp[jj] = zppt[jj] = zptt[jj] = zttt[jj] = 0.f;
    }
    for (int h = 0; h < NH; ++h) {
      float yv = ylds[h * 64 + lane];
      float f1 = fmaf(-yv, yv, 1.0f);             // tanh'
      float f2 = -2.0f * (yv * f1);               // tanh''
      float f3 = f1 * fmaf(6.0f * yv, yv, -2.0f); // tanh'''
      const float* m = Wm + h * 12;               // wave-uniform -> s_load
      float pr1 = m[1] * f1, pr2 = m[2] * f1;
      float pr3 = m[3] * f2, pr4 = m[4] * f2, pr5 = m[5] * f2;
      float pr6 = m[6] * f3, pr7 = m[7] * f3, pr8 = m[8] * f3, pr9 = m[9] * f3;
      const float* w2r = W2 + h * NH + j0;        // wave-uniform -> s_load
#pragma unroll
      for (int jj = 0; jj < 4; ++jj) {
        float w = w2r[jj];
        z0[jj]   = fmaf(w, yv,  z0[jj]);
        zp[jj]   = fmaf(w, pr1, zp[jj]);
        zt[jj]   = fmaf(w, pr2, zt[jj]);
        zpp[jj]  = fmaf(w, pr3, zpp[jj]);
        zpt[jj]  = fmaf(w, pr4, zpt[jj]);
        ztt[jj]  = fmaf(w, pr5, ztt[jj]);
        zppp[jj] = fmaf(w, pr6, zppp[jj]);
        zppt[jj] = fmaf(w, pr7, zppt[jj]);
        zptt[jj] = fmaf(w, pr8, zptt[jj]);
        zttt[jj] = fmaf(w, pr9, zttt[jj]);
      }
    }
    // layer-2 tanh jet (Faa di Bruno, order 3) + W3 contraction
#pragma unroll
    for (int jj = 0; jj < 4; ++jj) {
      float y2 = fast_tanh(z0[jj]);
      float g1 = fmaf(-y2, y2, 1.0f);
      float g2 = -2.0f * (y2 * g1);
      float g3 = g1 * fmaf(6.0f * y2, y2, -2.0f);
      float gp = zp[jj], gt = zt[jj];
      float gpp = zpp[jj], gpt = zpt[jj], gtt = ztt[jj];
      float gp2 = gp * gp, gt2 = gt * gt;
      float w3 = W3[j0 + jj];
      T_p  = fmaf(w3, g1 * gp, T_p);
      T_t  = fmaf(w3, g1 * gt, T_t);
      T_pp = fmaf(w3, fmaf(g2, gp2, g1 * gpp), T_pp);
      T_pt = fmaf(w3, fmaf(g2, gp * gt, g1 * gpt), T_pt);
      T_tt = fmaf(w3, fmaf(g2, gt2, g1 * gtt), T_tt);
      T_ppp = fmaf(w3, fmaf(g3, gp2 * gp, fmaf(3.0f * g2, gp * gpp, g1 * zppp[jj])), T_ppp);
      T_ppt = fmaf(w3, fmaf(g3, gp2 * gt, fmaf(g2, fmaf(2.0f, gp * gpt, gt * gpp), g1 * zppt[jj])), T_ppt);
      T_ptt = fmaf(w3, fmaf(g3, gp * gt2, fmaf(g2, fmaf(2.0f, gt * gpt, gp * gtt), g1 * zptt[jj])), T_ptt);
      T_ttt = fmaf(w3, fmaf(g3, gt2 * gt, fmaf(3.0f * g2, gt * gtt, g1 * zttt[jj])), T_ttt);
    }
  }

  // ---- reduce partials across the 4 waves ----
  red[(0 * 4 + wave) * 64 + lane] = T_p;
  red[(1 * 4 + wave) * 64 + lane] = T_t;
  red[(2 * 4 + wave) * 64 + lane] = T_pp;
  red[(3 * 4 + wave) * 64 + lane] = T_pt;
  red[(4 * 4 + wave) * 64 + lane] = T_tt;
  red[(5 * 4 + wave) * 64 + lane] = T_ppp;
  red[(6 * 4 + wave) * 64 + lane] = T_ppt;
  red[(7 * 4 + wave) * 64 + lane] = T_ptt;
  red[(8 * 4 + wave) * 64 + lane] = T_ttt;
  __syncthreads();

  if (wave == 0 && pi < n) {
    float Tq[9];
#pragma unroll
    for (int k = 0; k < 9; ++k) {
      const float* r = red + k * 256 + lane;
      Tq[k] = (r[0] + r[64]) + (r[128] + r[192]);
    }
    float Tp = Tq[0], Tt = Tq[1], Tpp = Tq[2], Tpt = Tq[3], Ttt = Tq[4];
    float Tppp = Tq[5], Tppt = Tq[6], Tptt = Tq[7], Tttt = Tq[8];

    float s = sinf(t), c = cosf(t);
    float inv_s = 1.0f / s;
    float inv_s2 = inv_s * inv_s;

    float A = Tp * inv_s + Tt;          // u_theta
    float D = Tp * inv_s - Tt;          // u_phi
    float q1 = Tpt * inv_s - Tp * c * inv_s2;               // dt(T_p/s)
    float A_t = q1 + Ttt;
    float D_t = q1 - Ttt;
    float q2 = Tptt * inv_s - 2.0f * Tpt * c * inv_s2
             + Tp * (s * s + 2.0f * c * c) * inv_s2 * inv_s; // dtt(T_p/s)
    float A_tt = q2 + Tttt;
    float D_tt = q2 - Tttt;
    float A_pp = Tppp * inv_s + Tppt;
    float D_p  = Tpp * inv_s - Tpt;
    float D_pp = Tppp * inv_s - Tppt;

    float utt   = -(A_t * s + A * c);
    float uttt  = -(A_tt * s + 2.0f * A_t * c - A * s) * s + utt * c;
    float utpp  = -A_pp;
    float upht  = D_t * s + D * c;
    float uphtt = (D_tt * s + 2.0f * D_t * c - D * s) * s + upht * c;
    float upp   = D_p;
    float uppp  = D_pp;

    float r = radius[pi];
    float inv_r = 1.0f / r;
    float inv_r2 = inv_r * inv_r;
    float div_uh = (utt + upp) * inv_r * inv_s;
    float lap_t = s * inv_r2 * uttt + utpp * inv_s2 * inv_r2;
    float lap_p = s * inv_r2 * uphtt + uppp * inv_s2 * inv_r2;
    float comp = s * (lap_t * lap_t + lap_p * lap_p);
    float sv = -(A * hth[pi] + D * hph[pi]) - br[pi] * div_uh;
    float tg = div_uh - A * (s / c) * inv_r;

    out[pi]         = A;
    out[n + pi]     = D;
    out[2 * n + pi] = div_uh;
    out[3 * n + pi] = sv;
    out[4 * n + pi] = tg;
    out[5 * n + pi] = comp;
  }
}

extern "C" void kernel_launch(void* const* d_in, const int* in_sizes, int n_in,
                              void* d_out, int out_size, void* d_ws, size_t ws_size,
                              hipStream_t stream) {
  const float* phi    = (const float*)d_in[0];
  const float* theta  = (const float*)d_in[1];
  const float* radius = (const float*)d_in[2];
  const float* hth    = (const float*)d_in[3];
  const float* hph    = (const float*)d_in[4];
  const float* br     = (const float*)d_in[5];
  const float* W1     = (const float*)d_in[6];
  const float* b1     = (const float*)d_in[7];
  const float* W2     = (const float*)d_in[8];
  const float* b2     = (const float*)d_in[9];
  const float* W3     = (const float*)d_in[10];
  (void)d_in; (void)ws_size; (void)n_in; (void)out_size;

  float* Wm  = (float*)d_ws;           // 64*12 floats = 3 KB
  float* out = (float*)d_out;
  int n = in_sizes[0];

  prep_mono<<<1, 64, 0, stream>>>(W1, Wm);
  int nblocks = (n + 63) / 64;
  pinn_kernel<<<nblocks, 256, 0, stream>>>(
      phi, theta, radius, hth, hph, br, W1, b1, W2, b2, W3, Wm, out, n);
}

// Round 3
// 221.696 us; speedup vs baseline: 2.0254x; 1.0177x over previous
//
#include <hip/hip_runtime.h>
#include <hip/hip_bf16.h>

#define NH 64

__device__ __forceinline__ float fast_tanh(float x) {
  float ax = fabsf(x);
  float e  = __expf(-2.0f * ax);
  float y  = (1.0f - e) * __builtin_amdgcn_rcpf(1.0f + e);
  return copysignf(y, x);
}

// Monomials of layer-1 weights, padded to 12 floats/row.
// m[3..5] pre-scaled by -2 so tanh'' = (y*f1) folds the -2 for free:
//   true f2 = -2*y*f1;  pr_k = mono_k * f2 = (-2*mono_k) * (y*f1)
__global__ void prep_mono(const float* __restrict__ W1, float* __restrict__ Wm) {
  int h = threadIdx.x;
  if (h >= NH) return;
  float a = W1[h];
  float b = W1[NH + h];
  float* m = Wm + h * 12;
  m[0] = 1.0f; m[1] = a;              m[2] = b;
  m[3] = -2.0f * a * a; m[4] = -2.0f * a * b; m[5] = -2.0f * b * b;
  m[6] = a * a * a; m[7] = a * a * b; m[8] = a * b * b; m[9] = b * b * b;
  m[10] = 0.0f; m[11] = 0.0f;
}

// Block = 256 threads = 4 waves, handles 64 points.
// wave w owns j-range [16w, 16w+16); lane l owns point blockIdx*64 + l.
// __launch_bounds__(256,4): min 4 waves/EU -> VGPR cap 128, prevents the
// 48-VGPR allocation that spilled the 40 jet accumulators (R2 post-mortem).
__global__ __launch_bounds__(256, 4) void pinn_kernel(
    const float* __restrict__ phi, const float* __restrict__ theta,
    const float* __restrict__ radius, const float* __restrict__ hth,
    const float* __restrict__ hph, const float* __restrict__ br,
    const float* __restrict__ W1, const float* __restrict__ b1,
    const float* __restrict__ W2, const float* __restrict__ b2,
    const float* __restrict__ W3, const float* __restrict__ Wm,
    float* __restrict__ out, int n) {
  __shared__ float ylds[NH * 64];      // y[h][point]   16 KB
  __shared__ float red[9 * 4 * 64];    // partial T-derivs [kind][wave][point]  9 KB

  const int tid  = threadIdx.x;
  const int lane = tid & 63;
  const int wave = __builtin_amdgcn_readfirstlane(tid >> 6);
  const int pi   = blockIdx.x * 64 + lane;

  float p = 0.0f, t = 0.0f;
  if (pi < n) { p = phi[pi]; t = theta[pi]; }

  // ---- phase 1: layer-1 activations, wave w computes h in [16w,16w+16) ----
  for (int k = 0; k < 16; ++k) {
    int h = wave * 16 + k;            // wave-uniform
    float z = fmaf(p, W1[h], fmaf(t, W1[NH + h], b1[h]));
    ylds[h * 64 + lane] = fast_tanh(z);
  }
  __syncthreads();

  // ---- phase 2: jet through layer 2 for this wave's 16 j's ----
  const int jbase = wave * 16;
  float T_p = 0.f, T_t = 0.f, T_pp = 0.f, T_pt = 0.f, T_tt = 0.f;
  float T_ppp = 0.f, T_ppt = 0.f, T_ptt = 0.f, T_ttt = 0.f;

  for (int jb = 0; jb < 4; ++jb) {
    const int j0 = jbase + jb * 4;    // wave-uniform
    float z0[4], zp[4], zt[4], zpp[4], zpt[4], ztt[4];
    float zppp[4], zppt[4], zptt[4], zttt[4];
#pragma unroll
    for (int jj = 0; jj < 4; ++jj) {
      z0[jj] = b2[j0 + jj];
      zp[jj] = zt[jj] = zpp[jj] = zpt[jj] = ztt[jj] = 0.f;
      zppp[jj] = zppt[jj] = zptt[jj] = zttt[jj] = 0.f;
    }
    for (int h = 0; h < NH; ++h) {
      float yv = ylds[h * 64 + lane];
      float f1  = fmaf(-yv, yv, 1.0f);          // tanh'  = 1 - y^2
      float f2a = yv * f1;                      // -tanh''/2  (mono pre-scaled)
      float f3  = f1 * fmaf(-6.0f, f1, 4.0f);   // tanh''' = f1*(6y^2-2) = f1*(4-6*f1)
      const float* m = Wm + h * 12;             // wave-uniform -> s_load
      float pr1 = m[1] * f1, pr2 = m[2] * f1;
      float pr3 = m[3] * f2a, pr4 = m[4] * f2a, pr5 = m[5] * f2a;
      float pr6 = m[6] * f3, pr7 = m[7] * f3, pr8 = m[8] * f3, pr9 = m[9] * f3;
      const float* w2r = W2 + h * NH + j0;      // wave-uniform -> s_load
#pragma unroll
      for (int jj = 0; jj < 4; ++jj) {
        float w = w2r[jj];
        z0[jj]   = fmaf(w, yv,  z0[jj]);
        zp[jj]   = fmaf(w, pr1, zp[jj]);
        zt[jj]   = fmaf(w, pr2, zt[jj]);
        zpp[jj]  = fmaf(w, pr3, zpp[jj]);
        zpt[jj]  = fmaf(w, pr4, zpt[jj]);
        ztt[jj]  = fmaf(w, pr5, ztt[jj]);
        zppp[jj] = fmaf(w, pr6, zppp[jj]);
        zppt[jj] = fmaf(w, pr7, zppt[jj]);
        zptt[jj] = fmaf(w, pr8, zptt[jj]);
        zttt[jj] = fmaf(w, pr9, zttt[jj]);
      }
    }
    // layer-2 tanh jet (Faa di Bruno, order 3) + W3 contraction
#pragma unroll
    for (int jj = 0; jj < 4; ++jj) {
      float y2 = fast_tanh(z0[jj]);
      float g1 = fmaf(-y2, y2, 1.0f);
      float g2 = -2.0f * (y2 * g1);
      float g3 = g1 * fmaf(-6.0f, g1, 4.0f);
      float gp = zp[jj], gt = zt[jj];
      float gpp = zpp[jj], gpt = zpt[jj], gtt = ztt[jj];
      float gp2 = gp * gp, gt2 = gt * gt;
      float w3 = W3[j0 + jj];
      T_p  = fmaf(w3, g1 * gp, T_p);
      T_t  = fmaf(w3, g1 * gt, T_t);
      T_pp = fmaf(w3, fmaf(g2, gp2, g1 * gpp), T_pp);
      T_pt = fmaf(w3, fmaf(g2, gp * gt, g1 * gpt), T_pt);
      T_tt = fmaf(w3, fmaf(g2, gt2, g1 * gtt), T_tt);
      T_ppp = fmaf(w3, fmaf(g3, gp2 * gp, fmaf(3.0f * g2, gp * gpp, g1 * zppp[jj])), T_ppp);
      T_ppt = fmaf(w3, fmaf(g3, gp2 * gt, fmaf(g2, fmaf(2.0f, gp * gpt, gt * gpp), g1 * zppt[jj])), T_ppt);
      T_ptt = fmaf(w3, fmaf(g3, gp * gt2, fmaf(g2, fmaf(2.0f, gt * gpt, gp * gtt), g1 * zptt[jj])), T_ptt);
      T_ttt = fmaf(w3, fmaf(g3, gt2 * gt, fmaf(3.0f * g2, gt * gtt, g1 * zttt[jj])), T_ttt);
    }
  }

  // ---- reduce partials across the 4 waves ----
  red[(0 * 4 + wave) * 64 + lane] = T_p;
  red[(1 * 4 + wave) * 64 + lane] = T_t;
  red[(2 * 4 + wave) * 64 + lane] = T_pp;
  red[(3 * 4 + wave) * 64 + lane] = T_pt;
  red[(4 * 4 + wave) * 64 + lane] = T_tt;
  red[(5 * 4 + wave) * 64 + lane] = T_ppp;
  red[(6 * 4 + wave) * 64 + lane] = T_ppt;
  red[(7 * 4 + wave) * 64 + lane] = T_ptt;
  red[(8 * 4 + wave) * 64 + lane] = T_ttt;
  __syncthreads();

  if (wave == 0 && pi < n) {
    float Tq[9];
#pragma unroll
    for (int k = 0; k < 9; ++k) {
      const float* r = red + k * 256 + lane;
      Tq[k] = (r[0] + r[64]) + (r[128] + r[192]);
    }
    float Tp = Tq[0], Tt = Tq[1], Tpp = Tq[2], Tpt = Tq[3], Ttt = Tq[4];
    float Tppp = Tq[5], Tppt = Tq[6], Tptt = Tq[7], Tttt = Tq[8];

    float s = sinf(t), c = cosf(t);
    float inv_s = 1.0f / s;
    float inv_s2 = inv_s * inv_s;

    float A = Tp * inv_s + Tt;          // u_theta
    float D = Tp * inv_s - Tt;          // u_phi
    float q1 = Tpt * inv_s - Tp * c * inv_s2;               // dt(T_p/s)
    float A_t = q1 + Ttt;
    float D_t = q1 - Ttt;
    float q2 = Tptt * inv_s - 2.0f * Tpt * c * inv_s2
             + Tp * (s * s + 2.0f * c * c) * inv_s2 * inv_s; // dtt(T_p/s)
    float A_tt = q2 + Tttt;
    float D_tt = q2 - Tttt;
    float A_pp = Tppp * inv_s + Tppt;
    float D_p  = Tpp * inv_s - Tpt;
    float D_pp = Tppp * inv_s - Tppt;

    float utt   = -(A_t * s + A * c);
    float uttt  = -(A_tt * s + 2.0f * A_t * c - A * s) * s + utt * c;
    float utpp  = -A_pp;
    float upht  = D_t * s + D * c;
    float uphtt = (D_tt * s + 2.0f * D_t * c - D * s) * s + upht * c;
    float upp   = D_p;
    float uppp  = D_pp;

    float r = radius[pi];
    float inv_r = 1.0f / r;
    float inv_r2 = inv_r * inv_r;
    float div_uh = (utt + upp) * inv_r * inv_s;
    float lap_t = s * inv_r2 * uttt + utpp * inv_s2 * inv_r2;
    float lap_p = s * inv_r2 * uphtt + uppp * inv_s2 * inv_r2;
    float comp = s * (lap_t * lap_t + lap_p * lap_p);
    float sv = -(A * hth[pi] + D * hph[pi]) - br[pi] * div_uh;
    float tg = div_uh - A * (s / c) * inv_r;

    out[pi]         = A;
    out[n + pi]     = D;
    out[2 * n + pi] = div_uh;
    out[3 * n + pi] = sv;
    out[4 * n + pi] = tg;
    out[5 * n + pi] = comp;
  }
}

extern "C" void kernel_launch(void* const* d_in, const int* in_sizes, int n_in,
                              void* d_out, int out_size, void* d_ws, size_t ws_size,
                              hipStream_t stream) {
  const float* phi    = (const float*)d_in[0];
  const float* theta  = (const float*)d_in[1];
  const float* radius = (const float*)d_in[2];
  const float* hth    = (const float*)d_in[3];
  const float* hph    = (const float*)d_in[4];
  const float* br     = (const float*)d_in[5];
  const float* W1     = (const float*)d_in[6];
  const float* b1     = (const float*)d_in[7];
  const float* W2     = (const float*)d_in[8];
  const float* b2     = (const float*)d_in[9];
  const float* W3     = (const float*)d_in[10];
  (void)ws_size; (void)n_in; (void)out_size;

  float* Wm  = (float*)d_ws;           // 64*12 floats = 3 KB
  float* out = (float*)d_out;
  int n = in_sizes[0];

  prep_mono<<<1, 64, 0, stream>>>(W1, Wm);
  int nblocks = (n + 63) / 64;
  pinn_kernel<<<nblocks, 256, 0, stream>>>(
      phi, theta, radius, hth, hph, br, W1, b1, W2, b2, W3, Wm, out, n);
}

// Round 4
// 220.467 us; speedup vs baseline: 2.0367x; 1.0056x over previous
//
#include <hip/hip_runtime.h>
#include <hip/hip_bf16.h>

#define NH 64

typedef float v2f __attribute__((ext_vector_type(2)));

__device__ __forceinline__ float fast_tanh(float x) {
  float ax = fabsf(x);
  float e  = __expf(-2.0f * ax);
  float y  = (1.0f - e) * __builtin_amdgcn_rcpf(1.0f + e);
  return copysignf(y, x);
}

// Monomials of layer-1 weights, padded to 12 floats/row, PAIRED for packed math:
// pairs (m0,m1)=(1,a) (m2,m3)=(b,-2a^2) (m4,m5)=(-2ab,-2b^2) (m6,m7)=(a^3,a^2b)
// (m8,m9)=(ab^2,b^3).  The -2 factors fold tanh'' = -2*y*f1 into the table.
__global__ void prep_mono(const float* __restrict__ W1, float* __restrict__ Wm) {
  int h = threadIdx.x;
  if (h >= NH) return;
  float a = W1[h];
  float b = W1[NH + h];
  float* m = Wm + h * 12;
  m[0] = 1.0f;          m[1] = a;
  m[2] = b;             m[3] = -2.0f * a * a;
  m[4] = -2.0f * a * b; m[5] = -2.0f * b * b;
  m[6] = a * a * a;     m[7] = a * a * b;
  m[8] = a * b * b;     m[9] = b * b * b;
  m[10] = 0.0f; m[11] = 0.0f;
}

// Block = 256 threads = 4 waves, 64 points/block.
// wave w owns j-range [16w,16w+16) in 2 blocks of 8; lane l owns point blockIdx*64+l.
// Jet kinds packed in pairs -> v_pk_fma_f32 (2 FLOP/slot, the only path to 157 TF fp32).
__global__ __launch_bounds__(256, 4) void pinn_kernel(
    const float* __restrict__ phi, const float* __restrict__ theta,
    const float* __restrict__ radius, const float* __restrict__ hth,
    const float* __restrict__ hph, const float* __restrict__ br,
    const float* __restrict__ W1, const float* __restrict__ b1,
    const float* __restrict__ W2, const float* __restrict__ b2,
    const float* __restrict__ W3, const float* __restrict__ Wm,
    float* __restrict__ out, int n) {
  __shared__ float ylds[NH * 64];      // y[h][point]   16 KB
  __shared__ float red[9 * 4 * 64];    // partial T-derivs [kind][wave][point]  9 KB

  const int tid  = threadIdx.x;
  const int lane = tid & 63;
  const int wave = __builtin_amdgcn_readfirstlane(tid >> 6);
  const int pi   = blockIdx.x * 64 + lane;

  float p = 0.0f, t = 0.0f;
  if (pi < n) { p = phi[pi]; t = theta[pi]; }

  // ---- phase 1: layer-1 activations, wave w computes h in [16w,16w+16) ----
  for (int k = 0; k < 16; ++k) {
    int h = wave * 16 + k;            // wave-uniform
    float z = fmaf(p, W1[h], fmaf(t, W1[NH + h], b1[h]));
    ylds[h * 64 + lane] = fast_tanh(z);
  }
  __syncthreads();

  // ---- phase 2: jet through layer 2 for this wave's 16 j's ----
  const int jbase = wave * 16;
  float T_p = 0.f, T_t = 0.f, T_pp = 0.f, T_pt = 0.f, T_tt = 0.f;
  float T_ppp = 0.f, T_ppt = 0.f, T_ptt = 0.f, T_ttt = 0.f;

  for (int jb = 0; jb < 2; ++jb) {
    const int j0 = jbase + jb * 8;    // wave-uniform
    // acc[k][jj]: kind-pair k of j=j0+jj.
    // pairs: 0:(val,p) 1:(t,pp) 2:(pt,tt) 3:(ppp,ppt) 4:(ptt,ttt)
    v2f acc0[8], acc1[8], acc2[8], acc3[8], acc4[8];
#pragma unroll
    for (int jj = 0; jj < 8; ++jj) {
      acc0[jj] = (v2f){b2[j0 + jj], 0.f};
      acc1[jj] = (v2f){0.f, 0.f};
      acc2[jj] = (v2f){0.f, 0.f};
      acc3[jj] = (v2f){0.f, 0.f};
      acc4[jj] = (v2f){0.f, 0.f};
    }
    for (int h = 0; h < NH; ++h) {
      float yv = ylds[h * 64 + lane];
      float f1  = fmaf(-yv, yv, 1.0f);          // tanh'
      float f2a = yv * f1;                      // -tanh''/2 (mono pre-scaled)
      float f3  = f1 * fmaf(-6.0f, f1, 4.0f);   // tanh'''
      const v2f* mp = (const v2f*)(Wm + h * 12); // wave-uniform -> s_load pairs
      v2f F0 = (v2f){yv,  f1};
      v2f F1 = (v2f){f1,  f2a};
      v2f F2 = (v2f){f2a, f2a};
      v2f F3 = (v2f){f3,  f3};
      v2f P0 = F0 * mp[0];
      v2f P1 = F1 * mp[1];
      v2f P2 = F2 * mp[2];
      v2f P3 = F3 * mp[3];
      v2f P4 = F3 * mp[4];
      const float* w2r = W2 + h * NH + j0;      // wave-uniform -> s_load x8
#pragma unroll
      for (int jj = 0; jj < 8; ++jj) {
        float w = w2r[jj];
        v2f wv = (v2f){w, w};
        acc0[jj] = __builtin_elementwise_fma(wv, P0, acc0[jj]);
        acc1[jj] = __builtin_elementwise_fma(wv, P1, acc1[jj]);
        acc2[jj] = __builtin_elementwise_fma(wv, P2, acc2[jj]);
        acc3[jj] = __builtin_elementwise_fma(wv, P3, acc3[jj]);
        acc4[jj] = __builtin_elementwise_fma(wv, P4, acc4[jj]);
      }
    }
    // layer-2 tanh jet (Faa di Bruno, order 3) + W3 contraction
#pragma unroll
    for (int jj = 0; jj < 8; ++jj) {
      float z0   = acc0[jj].x, gp  = acc0[jj].y;
      float gt   = acc1[jj].x, gpp = acc1[jj].y;
      float gpt  = acc2[jj].x, gtt = acc2[jj].y;
      float zppp = acc3[jj].x, zppt = acc3[jj].y;
      float zptt = acc4[jj].x, zttt = acc4[jj].y;
      float y2 = fast_tanh(z0);
      float g1 = fmaf(-y2, y2, 1.0f);
      float g2 = -2.0f * (y2 * g1);
      float g3 = g1 * fmaf(-6.0f, g1, 4.0f);
      float gp2 = gp * gp, gt2 = gt * gt;
      float w3 = W3[j0 + jj];
      T_p  = fmaf(w3, g1 * gp, T_p);
      T_t  = fmaf(w3, g1 * gt, T_t);
      T_pp = fmaf(w3, fmaf(g2, gp2, g1 * gpp), T_pp);
      T_pt = fmaf(w3, fmaf(g2, gp * gt, g1 * gpt), T_pt);
      T_tt = fmaf(w3, fmaf(g2, gt2, g1 * gtt), T_tt);
      T_ppp = fmaf(w3, fmaf(g3, gp2 * gp, fmaf(3.0f * g2, gp * gpp, g1 * zppp)), T_ppp);
      T_ppt = fmaf(w3, fmaf(g3, gp2 * gt, fmaf(g2, fmaf(2.0f, gp * gpt, gt * gpp), g1 * zppt)), T_ppt);
      T_ptt = fmaf(w3, fmaf(g3, gp * gt2, fmaf(g2, fmaf(2.0f, gt * gpt, gp * gtt), g1 * zptt)), T_ptt);
      T_ttt = fmaf(w3, fmaf(g3, gt2 * gt, fmaf(3.0f * g2, gt * gtt, g1 * zttt)), T_ttt);
    }
  }

  // ---- reduce partials across the 4 waves ----
  red[(0 * 4 + wave) * 64 + lane] = T_p;
  red[(1 * 4 + wave) * 64 + lane] = T_t;
  red[(2 * 4 + wave) * 64 + lane] = T_pp;
  red[(3 * 4 + wave) * 64 + lane] = T_pt;
  red[(4 * 4 + wave) * 64 + lane] = T_tt;
  red[(5 * 4 + wave) * 64 + lane] = T_ppp;
  red[(6 * 4 + wave) * 64 + lane] = T_ppt;
  red[(7 * 4 + wave) * 64 + lane] = T_ptt;
  red[(8 * 4 + wave) * 64 + lane] = T_ttt;
  __syncthreads();

  if (wave == 0 && pi < n) {
    float Tq[9];
#pragma unroll
    for (int k = 0; k < 9; ++k) {
      const float* r = red + k * 256 + lane;
      Tq[k] = (r[0] + r[64]) + (r[128] + r[192]);
    }
    float Tp = Tq[0], Tt = Tq[1], Tpp = Tq[2], Tpt = Tq[3], Ttt = Tq[4];
    float Tppp = Tq[5], Tppt = Tq[6], Tptt = Tq[7], Tttt = Tq[8];

    float s = sinf(t), c = cosf(t);
    float inv_s = 1.0f / s;
    float inv_s2 = inv_s * inv_s;

    float A = Tp * inv_s + Tt;          // u_theta
    float D = Tp * inv_s - Tt;          // u_phi
    float q1 = Tpt * inv_s - Tp * c * inv_s2;               // dt(T_p/s)
    float A_t = q1 + Ttt;
    float D_t = q1 - Ttt;
    float q2 = Tptt * inv_s - 2.0f * Tpt * c * inv_s2
             + Tp * (s * s + 2.0f * c * c) * inv_s2 * inv_s; // dtt(T_p/s)
    float A_tt = q2 + Tttt;
    float D_tt = q2 - Tttt;
    float A_pp = Tppp * inv_s + Tppt;
    float D_p  = Tpp * inv_s - Tpt;
    float D_pp = Tppp * inv_s - Tppt;

    float utt   = -(A_t * s + A * c);
    float uttt  = -(A_tt * s + 2.0f * A_t * c - A * s) * s + utt * c;
    float utpp  = -A_pp;
    float upht  = D_t * s + D * c;
    float uphtt = (D_tt * s + 2.0f * D_t * c - D * s) * s + upht * c;
    float upp   = D_p;
    float uppp  = D_pp;

    float r = radius[pi];
    float inv_r = 1.0f / r;
    float inv_r2 = inv_r * inv_r;
    float div_uh = (utt + upp) * inv_r * inv_s;
    float lap_t = s * inv_r2 * uttt + utpp * inv_s2 * inv_r2;
    float lap_p = s * inv_r2 * uphtt + uppp * inv_s2 * inv_r2;
    float comp = s * (lap_t * lap_t + lap_p * lap_p);
    float sv = -(A * hth[pi] + D * hph[pi]) - br[pi] * div_uh;
    float tg = div_uh - A * (s / c) * inv_r;

    out[pi]         = A;
    out[n + pi]     = D;
    out[2 * n + pi] = div_uh;
    out[3 * n + pi] = sv;
    out[4 * n + pi] = tg;
    out[5 * n + pi] = comp;
  }
}

extern "C" void kernel_launch(void* const* d_in, const int* in_sizes, int n_in,
                              void* d_out, int out_size, void* d_ws, size_t ws_size,
                              hipStream_t stream) {
  const float* phi    = (const float*)d_in[0];
  const float* theta  = (const float*)d_in[1];
  const float* radius = (const float*)d_in[2];
  const float* hth    = (const float*)d_in[3];
  const float* hph    = (const float*)d_in[4];
  const float* br     = (const float*)d_in[5];
  const float* W1     = (const float*)d_in[6];
  const float* b1     = (const float*)d_in[7];
  const float* W2     = (const float*)d_in[8];
  const float* b2     = (const float*)d_in[9];
  const float* W3     = (const float*)d_in[10];
  (void)ws_size; (void)n_in; (void)out_size;

  float* Wm  = (float*)d_ws;           // 64*12 floats = 3 KB
  float* out = (float*)d_out;
  int n = in_sizes[0];

  prep_mono<<<1, 64, 0, stream>>>(W1, Wm);
  int nblocks = (n + 63) / 64;
  pinn_kernel<<<nblocks, 256, 0, stream>>>(
      phi, theta, radius, hth, hph, br, W1, b1, W2, b2, W3, Wm, out, n);
}